// Round 8
// baseline (202.442 us; speedup 1.0000x reference)
//
#include <hip/hip_runtime.h>
#include <hip/hip_bf16.h>
#include <stdint.h>

#define NP 30000
#define BBINS 80
#define INCH 16
#define OUTCH 32
#define KDIM 1280       // BBINS*INCH
#define NDIM 512        // OUTCH*TBINS
#define KSTEPS 40       // KDIM/32
#define NROWS (NP * BBINS)   // 2,400,000
#define MTILES 118           // ceil(30000/256)
#define PREP_BLOCKS 2560

typedef __bf16 bf16x8 __attribute__((ext_vector_type(8)));
typedef __bf16 bf16x4 __attribute__((ext_vector_type(4)));
typedef float f32x4 __attribute__((ext_vector_type(4)));

__device__ __forceinline__ void async_ld16(const void* g, void* l) {
    __builtin_amdgcn_global_load_lds(
        (const __attribute__((address_space(1))) unsigned int*)g,
        (__attribute__((address_space(3))) unsigned int*)l,
        16, 0, 0);
}

// ---------------------------------------------------------------------------
// Fused prep + gather (independent roles by blockIdx; both write d_ws only).
//
// prep role (blocks 0..2559): PW[kc][n][slot][e] bf16; slot s holds data
// k-chunk s ^ ((n>>1)&3). lw[k][n] = W[(b+5t)%80][c][o], k=b*16+c, n=o*16+t.
//
// gather role: 4 lanes per (patch,bin) row; conn LDS-staged; h written
// PRE-SWIZZLED (R5-verified): chunk cl of patch p at slot cl ^ ((p>>1)&3)
// within the 64-B kstep group (bin>>1). Stores stay full-line coalesced.
// ---------------------------------------------------------------------------
__global__ __launch_bounds__(256) void prep_gather(
    const float* __restrict__ x,
    const int*   __restrict__ cidx,
    const float* __restrict__ cval,
    const float* __restrict__ w,
    __bf16* __restrict__ pw,
    __bf16* __restrict__ h) {
    __shared__ int   ci[192];
    __shared__ float cv[192];

    if (blockIdx.x < PREP_BLOCKS) {
        int gid = blockIdx.x * 256 + threadIdx.x;        // 655360 total
        int e  = gid & 7;
        int qs = (gid >> 3) & 3;                          // slot
        int n  = (gid >> 5) & 511;
        int kc = gid >> 14;                               // 0..39
        int kp = kc * 32 + ((qs ^ ((n >> 1) & 3)) << 3) + e;
        int b = kp >> 4, c = kp & 15;
        int o = n >> 4,  t = n & 15;
        int bid = (b + 5 * t) % BBINS;
        pw[gid] = (__bf16)w[(bid * INCH + c) * OUTCH + o];
        return;
    }

    const int t  = threadIdx.x;
    const int r0 = (blockIdx.x - PREP_BLOCKS) * 64;

    if (t < 48)
        ((int4*)ci)[t] = ((const int4*)(cidx + (size_t)r0 * 3))[t];
    else if (t >= 64 && t < 112)
        ((float4*)cv)[t - 64] = ((const float4*)(cval + (size_t)r0 * 3))[t - 64];
    __syncthreads();

    const int rl = t >> 2;               // 0..63
    const int q  = t & 3;                // channel quad
    const int i0 = ci[rl * 3 + 0], i1 = ci[rl * 3 + 1], i2 = ci[rl * 3 + 2];
    const float v0 = cv[rl * 3 + 0], v1 = cv[rl * 3 + 1], v2 = cv[rl * 3 + 2];

    const float4 a = *(const float4*)(x + (size_t)i0 * 16 + q * 4);
    const float4 b = *(const float4*)(x + (size_t)i1 * 16 + q * 4);
    const float4 c = *(const float4*)(x + (size_t)i2 * 16 + q * 4);
    bf16x4 hv;
    hv[0] = (__bf16)(v0 * a.x + v1 * b.x + v2 * c.x);
    hv[1] = (__bf16)(v0 * a.y + v1 * b.y + v2 * c.y);
    hv[2] = (__bf16)(v0 * a.z + v1 * b.z + v2 * c.z);
    hv[3] = (__bf16)(v0 * a.w + v1 * b.w + v2 * c.w);

    const int r   = r0 + rl;
    const int p   = r / 80;
    const int bin = r - p * 80;
    const int cl   = 2 * (bin & 1) + (q >> 1);           // chunk within 64-B group
    const int slot = cl ^ ((p >> 1) & 3);
    const size_t off = (size_t)p * 2560 + (bin >> 1) * 64 + slot * 16 + (q & 1) * 8;
    *(bf16x4*)((char*)h + off) = hv;
}

// ---------------------------------------------------------------------------
// GEMM + max-over-t.  512 threads (8 waves, 4x2), tile 256x256.
// AITER-style K-loop: 3-deep LDS ring, all staging via global_load_lds,
// and `s_waitcnt vmcnt(4); s_barrier` instead of __syncthreads — the 4
// just-issued stage(kc+2) loads stay IN FLIGHT across the barrier, so each
// stage has ~2 ksteps of latency budget (the R7 killer was the vmcnt(0)
// drain of same-iteration loads at every barrier).
// A pre-swizzled by gather, B by prep -> verbatim staging, conflict-free
// ds_read_b128 (XOR keys congruent because mbase = 256*m).
// ---------------------------------------------------------------------------
__global__ __launch_bounds__(512, 2) void gemm_max(
    const __bf16* __restrict__ h,
    const __bf16* __restrict__ pw,
    float* __restrict__ out) {

    __shared__ __align__(16) char Abuf[3][16384];   // 256 rows x 64 B, ring
    __shared__ __align__(16) char Bbuf[3][16384];   // 256 cols x 64 B, ring

    const int bid = blockIdx.x;
    const int m    = (bid >> 4) * 8 + (bid & 7);     // 0..119
    const int ncol = (bid >> 3) & 1;                 // 0/1 (pairs g,g+8 same XCD)
    if (m >= MTILES) return;                         // 4 dead pad blocks
    const int mbase = m * 256;

    const int tid  = threadIdx.x;
    const int lane = tid & 63;
    const int wave = tid >> 6;
    const int wm = wave >> 1;            // 0..3
    const int wc = wave & 1;             // 0..1

    int a_off[4], b_off[8];
    {
        const int ml = lane & 15, q = lane >> 4;
        const int swz = (q ^ ((ml >> 1) & 3)) << 4;
#pragma unroll
        for (int i = 0; i < 4; ++i)
            a_off[i] = (wm * 64 + i * 16 + ml) * 64 + swz;
#pragma unroll
        for (int j = 0; j < 8; ++j)
            b_off[j] = (wc * 128 + j * 16 + ml) * 64 + swz;
    }

    f32x4 acc[4][8];
#pragma unroll
    for (int i = 0; i < 4; ++i)
#pragma unroll
        for (int j = 0; j < 8; ++j)
            acc[i][j] = (f32x4){0.f, 0.f, 0.f, 0.f};

    // Staging: thread covers A rows (tid>>2) and (tid>>2)+128, chunk tid&3,
    // plus two 16-B B chunks. All dsts are linear tid*16 (wave-uniform base
    // + lane*16, as global_load_lds requires). Sources are pre-swizzled.
    const int aq = tid & 3;
    int rG0 = mbase + (tid >> 2);
    int rG1 = rG0 + 128;
    if (rG0 > NP - 1) rG0 = NP - 1;   // dup last row; epilogue guards stores
    if (rG1 > NP - 1) rG1 = NP - 1;
    const char* aSrc0 = (const char*)h + (size_t)rG0 * 2560 + aq * 16;
    const char* aSrc1 = (const char*)h + (size_t)rG1 * 2560 + aq * 16;
    const char* bSrc  = (const char*)pw + ncol * 16384 + tid * 16;
    const int ldsOff  = tid * 16;

#define STAGE(KC, BUF)                                                   \
    do {                                                                 \
        async_ld16(aSrc0 + (KC) * 64, Abuf[BUF] + ldsOff);               \
        async_ld16(aSrc1 + (KC) * 64, Abuf[BUF] + 8192 + ldsOff);        \
        async_ld16(bSrc + (size_t)(KC) * 32768, Bbuf[BUF] + ldsOff);     \
        async_ld16(bSrc + (size_t)(KC) * 32768 + 8192,                   \
                   Bbuf[BUF] + 8192 + ldsOff);                           \
    } while (0)

// Wait until at most N VMEM ops outstanding (in-order retirement => the
// older stage is complete), then block barrier. NOT a full vmcnt(0) drain.
#define WAITB(N) asm volatile("s_waitcnt vmcnt(" #N ")\n\ts_barrier" ::: "memory")

    STAGE(0, 0);
    STAGE(1, 1);
    WAITB(4);                            // stage(0) done; stage(1) in flight

    for (int kc = 0; kc < KSTEPS; ++kc) {
        const int cur = kc % 3;
        if (kc + 2 < KSTEPS)
            STAGE(kc + 2, (kc + 2) % 3); // lands ~2 ksteps from now

        bf16x8 af[4], bfr[8];
#pragma unroll
        for (int i = 0; i < 4; ++i)
            af[i] = *(const bf16x8*)(Abuf[cur] + a_off[i]);
#pragma unroll
        for (int j = 0; j < 8; ++j)
            bfr[j] = *(const bf16x8*)(Bbuf[cur] + b_off[j]);
#pragma unroll
        for (int i = 0; i < 4; ++i)
#pragma unroll
            for (int j = 0; j < 8; ++j)
                acc[i][j] = __builtin_amdgcn_mfma_f32_16x16x32_bf16(
                    af[i], bfr[j], acc[i][j], 0, 0, 0);

        if (kc + 2 < KSTEPS)      WAITB(4);   // stage(kc+1) done, kc+2 in flight
        else if (kc + 1 < KSTEPS) WAITB(0);   // tail: nothing newer outstanding
    }
#undef STAGE
#undef WAITB

    // ---- epilogue: max over t (t = col = lane&15), store o = n>>4
    const int rgrp = lane >> 4;
    const int tl   = lane & 15;
#pragma unroll
    for (int i = 0; i < 4; ++i) {
#pragma unroll
        for (int j = 0; j < 8; ++j) {
            float v0 = acc[i][j][0], v1 = acc[i][j][1];
            float v2 = acc[i][j][2], v3 = acc[i][j][3];
#pragma unroll
            for (int off = 1; off < 16; off <<= 1) {
                v0 = fmaxf(v0, __shfl_xor(v0, off));
                v1 = fmaxf(v1, __shfl_xor(v1, off));
                v2 = fmaxf(v2, __shfl_xor(v2, off));
                v3 = fmaxf(v3, __shfl_xor(v3, off));
            }
            if (tl == 0) {
                const int o  = ncol * 16 + wc * 8 + j;
                const int pr = mbase + wm * 64 + i * 16 + rgrp * 4;
                if (pr + 0 < NP) out[(pr + 0) * 32 + o] = v0;
                if (pr + 1 < NP) out[(pr + 1) * 32 + o] = v1;
                if (pr + 2 < NP) out[(pr + 2) * 32 + o] = v2;
                if (pr + 3 < NP) out[(pr + 3) * 32 + o] = v3;
            }
        }
    }
}

extern "C" void kernel_launch(void* const* d_in, const int* in_sizes, int n_in,
                              void* d_out, int out_size, void* d_ws, size_t ws_size,
                              hipStream_t stream) {
    const float* x    = (const float*)d_in[0];
    const int*   cidx = (const int*)d_in[1];
    const float* cval = (const float*)d_in[2];
    const float* w    = (const float*)d_in[3];
    float* out = (float*)d_out;

    __bf16* pw = (__bf16*)d_ws;                               // 1.31 MB
    __bf16* h  = (__bf16*)((char*)d_ws + (2 << 20));          // 76.8 MB @ +2MB

    hipLaunchKernelGGL(prep_gather, dim3(PREP_BLOCKS + NROWS / 64), dim3(256), 0,
                       stream, x, cidx, cval, w, pw, h);
    hipLaunchKernelGGL(gemm_max, dim3(240), dim3(512), 0, stream,
                       h, (const __bf16*)pw, out);
}